// Round 2
// baseline (523.431 us; speedup 1.0000x reference)
//
#include <hip/hip_runtime.h>

// Problem constants (fixed by reference setup_inputs)
#define NB 32
#define NC 128
#define NH 63
#define NW 63
#define OH 30          // (63-5)/2+1
#define OW 30
#define CCH 32         // channels per LDS chunk
#define NCHUNK (NC/CCH)
#define CPAD 36        // padded channel stride in band (float4-aligned, rotates banks)
#define BANDSZ (5*63*CPAD)  // 11340 floats = 45.4 KB

__global__ void init_tops(float* tops) {
    if (threadIdx.x < NB) tops[threadIdx.x] = 0.0f;
}

__global__ __launch_bounds__(512) void strip_kernel(const float* __restrict__ f,
                                                    float* __restrict__ tops) {
    const int b  = blockIdx.x / OH;
    const int oi = blockIdx.x % OH;
    const int y0 = oi * 2;
    const int t  = threadIdx.x;

    __shared__ float band[BANDSZ];     // [r][x][c-chunk], c-stride CPAD
    __shared__ float ssum[OW * 25];    // per-tile cosine row sums
    __shared__ float snorm[OW * 25];   // per-tile pixel norms (reused for tile maxes)

    for (int u = t; u < OW * 25; u += 512) ssum[u] = 0.0f;

    // ---- item decomposition: 450 items = 30 tiles x 15 row-pair blocks ----
    const bool active = t < 450;
    int tile = 0, r1 = 0, r2 = 0;
    if (active) {
        tile = t / 15;
        int rem = t % 15, p = 0;
        while (rem >= 5 - p) { rem -= 5 - p; ++p; }
        r1 = p; r2 = p + rem;          // r1 <= r2
    }
    const int x0 = 2 * tile;

    float acc[25];
    #pragma unroll
    for (int k = 0; k < 25; ++k) acc[k] = 0.0f;

    const float* fb = f + (size_t)b * NC * NH * NW;

    // ---- channel-chunked band staging + gram accumulation ----
    for (int ch = 0; ch < NCHUNK; ++ch) {
        __syncthreads();  // previous chunk's readers done (also orders ssum zeroing)
        const float* fc0 = fb + (size_t)(ch * CCH) * NH * NW + y0 * NW;
        for (int u = t; u < CCH * 5 * 63; u += 512) {
            const int x = u % 63;
            const int v = u / 63;
            const int r = v % 5;
            const int c = v / 5;
            band[(r * 63 + x) * CPAD + c] = fc0[(size_t)c * NH * NW + r * NW + x];
        }
        __syncthreads();
        if (active) {
            #pragma unroll
            for (int c4 = 0; c4 < CCH / 4; ++c4) {
                float4 av[5], bv[5];
                #pragma unroll
                for (int i = 0; i < 5; ++i)
                    av[i] = *(const float4*)&band[(r1 * 63 + x0 + i) * CPAD + c4 * 4];
                #pragma unroll
                for (int j = 0; j < 5; ++j)
                    bv[j] = *(const float4*)&band[(r2 * 63 + x0 + j) * CPAD + c4 * 4];
                #pragma unroll
                for (int i = 0; i < 5; ++i)
                    #pragma unroll
                    for (int j = 0; j < 5; ++j)
                        acc[i * 5 + j] += av[i].x * bv[j].x + av[i].y * bv[j].y
                                        + av[i].z * bv[j].z + av[i].w * bv[j].w;
            }
        }
    }

    // ---- norms from diagonal blocks ----
    if (active && r1 == r2) {
        #pragma unroll
        for (int i = 0; i < 5; ++i)
            snorm[tile * 25 + r1 * 5 + i] = sqrtf(acc[i * 5 + i]);
    }
    __syncthreads();

    // ---- cosine partial row-sums, scattered via LDS atomics ----
    if (active) {
        float n1[5], n2[5];
        #pragma unroll
        for (int i = 0; i < 5; ++i) {
            n1[i] = snorm[tile * 25 + r1 * 5 + i];
            n2[i] = snorm[tile * 25 + r2 * 5 + i];
        }
        float rowp[5] = {0, 0, 0, 0, 0}, colp[5] = {0, 0, 0, 0, 0};
        #pragma unroll
        for (int i = 0; i < 5; ++i)
            #pragma unroll
            for (int j = 0; j < 5; ++j) {
                const float denom = fmaxf(n1[i] * n2[j], 1e-6f);
                const float cv = 1.0f - acc[i * 5 + j] / denom;
                rowp[i] += cv;
                if (r1 != r2) colp[j] += cv;
            }
        #pragma unroll
        for (int i = 0; i < 5; ++i) atomicAdd(&ssum[tile * 25 + r1 * 5 + i], rowp[i]);
        if (r1 != r2) {
            #pragma unroll
            for (int j = 0; j < 5; ++j) atomicAdd(&ssum[tile * 25 + r2 * 5 + j], colp[j]);
        }
    }
    __syncthreads();

    // ---- per-tile max of mean, then strip max -> per-b atomic ----
    if (t < OW) {
        float m = -1e30f;
        #pragma unroll
        for (int p = 0; p < 25; ++p) m = fmaxf(m, ssum[t * 25 + p]);
        snorm[t] = m * (1.0f / 25.0f);
    }
    __syncthreads();
    if (t == 0) {
        float m = snorm[0];
        for (int q = 1; q < OW; ++q) m = fmaxf(m, snorm[q]);
        atomicMax((int*)&tops[b], __float_as_int(m));  // values >= 0
    }
}

__global__ void finalize(const float* __restrict__ tops,
                         const int* __restrict__ label,
                         float* __restrict__ out) {
    if (threadIdx.x == 0) {
        float fs = 0.0f, rs = 0.0f, fc = 0.0f, rc = 0.0f;
        for (int b = 0; b < NB; ++b) {
            const float tb = tops[b];
            const float lb = (float)label[b];
            fs += tb * lb;          fc += lb;
            rs += tb * (1.0f - lb); rc += (1.0f - lb);
        }
        const float loss = 1.0f - fs / fc + rs / rc;
        out[0] = fmaxf(loss, 0.0f);
    }
}

extern "C" void kernel_launch(void* const* d_in, const int* in_sizes, int n_in,
                              void* d_out, int out_size, void* d_ws, size_t ws_size,
                              hipStream_t stream) {
    const float* feature = (const float*)d_in[0];
    const int* label     = (const int*)d_in[1];
    float* out  = (float*)d_out;
    float* tops = (float*)d_ws;   // 32 floats of scratch

    init_tops<<<1, 64, 0, stream>>>(tops);
    strip_kernel<<<NB * OH, 512, 0, stream>>>(feature, tops);
    finalize<<<1, 64, 0, stream>>>(tops, label, out);
}

// Round 3
// 132.534 us; speedup vs baseline: 3.9494x; 3.9494x over previous
//
#include <hip/hip_runtime.h>

// Problem constants (fixed by reference setup_inputs)
#define NB 32
#define NC 128
#define NH 63
#define NW 63
#define OH 30          // (63-5)/2+1
#define OW 30
#define CCH 32         // channels per LDS chunk
#define NCHUNK (NC/CCH)
#define CPAD 36        // padded channel stride in band (float4-aligned)
#define BANDSZ (5*63*CPAD)  // 11340 floats = 45.4 KB

__global__ void init_tops(float* tops) {
    if (threadIdx.x < NB) tops[threadIdx.x] = 0.0f;
}

__global__ __launch_bounds__(512) void strip_kernel(const float* __restrict__ f,
                                                    float* __restrict__ tops) {
    const int b  = blockIdx.x / OH;
    const int oi = blockIdx.x % OH;
    const int y0 = oi * 2;
    const int t  = threadIdx.x;

    __shared__ float band[BANDSZ];     // [r][x][c-chunk], c-stride CPAD
    __shared__ float ssum[OW * 25];    // per-tile cosine row sums
    __shared__ float snorm[OW * 25];   // per-tile pixel norms (reused for tile maxes)

    for (int u = t; u < OW * 25; u += 512) ssum[u] = 0.0f;

    // ---- item decomposition: 450 items = 30 tiles x 15 row-pair blocks ----
    const bool active = t < 450;
    int tile = 0, r1 = 0, r2 = 0;
    if (active) {
        tile = t / 15;
        int rem = t % 15, p = 0;
        while (rem >= 5 - p) { rem -= 5 - p; ++p; }
        r1 = p; r2 = p + rem;          // r1 <= r2
    }
    const int x0 = 2 * tile;

    float acc[25];
    #pragma unroll
    for (int k = 0; k < 25; ++k) acc[k] = 0.0f;

    const float* fb = f + (size_t)b * NC * NH * NW;

    // ---- channel-chunked band staging + gram accumulation ----
    for (int ch = 0; ch < NCHUNK; ++ch) {
        __syncthreads();  // previous chunk's readers done (also orders ssum zeroing)
        const float* fc0 = fb + (size_t)(ch * CCH) * NH * NW + y0 * NW;
        for (int u = t; u < CCH * 5 * 63; u += 512) {
            const int x = u % 63;
            const int v = u / 63;
            const int r = v % 5;
            const int c = v / 5;
            band[(r * 63 + x) * CPAD + c] = fc0[(size_t)c * NH * NW + r * NW + x];
        }
        __syncthreads();
        if (active) {
            // keep live set small: av[5] resident, bv loaded one at a time
            #pragma unroll 1
            for (int c4 = 0; c4 < CCH / 4; ++c4) {
                float4 av[5];
                #pragma unroll
                for (int i = 0; i < 5; ++i)
                    av[i] = *(const float4*)&band[(r1 * 63 + x0 + i) * CPAD + c4 * 4];
                #pragma unroll
                for (int j = 0; j < 5; ++j) {
                    const float4 bv = *(const float4*)&band[(r2 * 63 + x0 + j) * CPAD + c4 * 4];
                    #pragma unroll
                    for (int i = 0; i < 5; ++i)
                        acc[i * 5 + j] += av[i].x * bv.x + av[i].y * bv.y
                                        + av[i].z * bv.z + av[i].w * bv.w;
                }
            }
        }
    }

    // ---- norms from diagonal blocks ----
    if (active && r1 == r2) {
        #pragma unroll
        for (int i = 0; i < 5; ++i)
            snorm[tile * 25 + r1 * 5 + i] = sqrtf(acc[i * 5 + i]);
    }
    __syncthreads();

    // ---- cosine partial row-sums, scattered via LDS atomics ----
    if (active) {
        float n1[5], n2[5];
        #pragma unroll
        for (int i = 0; i < 5; ++i) {
            n1[i] = snorm[tile * 25 + r1 * 5 + i];
            n2[i] = snorm[tile * 25 + r2 * 5 + i];
        }
        float rowp[5] = {0, 0, 0, 0, 0}, colp[5] = {0, 0, 0, 0, 0};
        #pragma unroll
        for (int i = 0; i < 5; ++i)
            #pragma unroll
            for (int j = 0; j < 5; ++j) {
                const float denom = fmaxf(n1[i] * n2[j], 1e-6f);
                const float cv = 1.0f - acc[i * 5 + j] / denom;
                rowp[i] += cv;
                if (r1 != r2) colp[j] += cv;
            }
        #pragma unroll
        for (int i = 0; i < 5; ++i) atomicAdd(&ssum[tile * 25 + r1 * 5 + i], rowp[i]);
        if (r1 != r2) {
            #pragma unroll
            for (int j = 0; j < 5; ++j) atomicAdd(&ssum[tile * 25 + r2 * 5 + j], colp[j]);
        }
    }
    __syncthreads();

    // ---- per-tile max of mean, then strip max -> per-b atomic ----
    if (t < OW) {
        float m = -1e30f;
        #pragma unroll
        for (int p = 0; p < 25; ++p) m = fmaxf(m, ssum[t * 25 + p]);
        snorm[t] = m * (1.0f / 25.0f);
    }
    __syncthreads();
    if (t == 0) {
        float m = snorm[0];
        for (int q = 1; q < OW; ++q) m = fmaxf(m, snorm[q]);
        atomicMax((int*)&tops[b], __float_as_int(m));  // values >= 0
    }
}

__global__ void finalize(const float* __restrict__ tops,
                         const int* __restrict__ label,
                         float* __restrict__ out) {
    if (threadIdx.x == 0) {
        float fs = 0.0f, rs = 0.0f, fc = 0.0f, rc = 0.0f;
        for (int b = 0; b < NB; ++b) {
            const float tb = tops[b];
            const float lb = (float)label[b];
            fs += tb * lb;          fc += lb;
            rs += tb * (1.0f - lb); rc += (1.0f - lb);
        }
        const float loss = 1.0f - fs / fc + rs / rc;
        out[0] = fmaxf(loss, 0.0f);
    }
}

extern "C" void kernel_launch(void* const* d_in, const int* in_sizes, int n_in,
                              void* d_out, int out_size, void* d_ws, size_t ws_size,
                              hipStream_t stream) {
    const float* feature = (const float*)d_in[0];
    const int* label     = (const int*)d_in[1];
    float* out  = (float*)d_out;
    float* tops = (float*)d_ws;   // 32 floats of scratch

    init_tops<<<1, 64, 0, stream>>>(tops);
    strip_kernel<<<NB * OH, 512, 0, stream>>>(feature, tops);
    finalize<<<1, 64, 0, stream>>>(tops, label, out);
}

// Round 4
// 97.569 us; speedup vs baseline: 5.3647x; 1.3584x over previous
//
#include <hip/hip_runtime.h>

// Problem constants (fixed by reference setup_inputs)
#define NB 32
#define NC 128
#define NH 63
#define NW 63
#define OH 30          // (63-5)/2+1
#define OW 30
#define CCH 16         // channels per LDS chunk
#define NCHUNK (NC/CCH)
#define CPAD 20        // padded channel stride (float4-aligned, rotates banks)
#define BANDSZ (5*63*CPAD)   // 6300 floats = 25.2 KB

__global__ void init_tops(float* tops) {
    if (threadIdx.x < NB) tops[threadIdx.x] = 0.0f;
}

__global__ __launch_bounds__(512) void strip_kernel(const float* __restrict__ f,
                                                    float* __restrict__ tops) {
    // XCD-aware swizzle: consecutive logical strips (same b, adjacent oi, 60% row
    // overlap) land on the same XCD for L2 reuse. Bijective: 960 = 8 * 120.
    const int lb = (blockIdx.x & 7) * (NB * OH / 8) + (blockIdx.x >> 3);
    const int b  = lb / OH;
    const int oi = lb % OH;
    const int y0 = oi * 2;
    const int t  = threadIdx.x;

    __shared__ float band[BANDSZ];     // [r][x][c-chunk], c-stride CPAD
    __shared__ float ssum[OW * 25];    // per-tile cosine row sums
    __shared__ float snorm[OW * 25];   // per-tile pixel norms (reused for tile maxes)

    for (int u = t; u < OW * 25; u += 512) ssum[u] = 0.0f;

    // ---- item decomposition: 450 items = 30 tiles x 15 row-pair blocks ----
    const bool active = t < 450;
    int tile = 0, r1 = 0, r2 = 0;
    if (active) {
        tile = t / 15;
        int rem = t % 15, p = 0;
        while (rem >= 5 - p) { rem -= 5 - p; ++p; }
        r1 = p; r2 = p + rem;          // r1 <= r2
    }
    const int x0 = 2 * tile;
    const int baseA = (r1 * 63 + x0) * CPAD;
    const int baseB = (r2 * 63 + x0) * CPAD;

    float acc[25];
    #pragma unroll
    for (int k = 0; k < 25; ++k) acc[k] = 0.0f;

    // ---- staging geometry: 504 threads, each owns (x, v); 10 elems/chunk with
    //      compile-time-constant offsets: c = 2v + k/5, r = k%5 (since 10*v ≡ 0 mod 5)
    const bool stg = t < 504;
    const int sx = t % 63;
    const int sv = t / 63;
    const float* fb = f + (size_t)b * NC * NH * NW;
    const float* gp = fb + (size_t)(2 * sv) * (NH * NW) + y0 * NW + sx;
    const int lbase = sx * CPAD + 2 * sv;

#define GOFF(k) ((k >= 5 ? NH * NW : 0) + (k % 5) * NW)
#define WOFF(k) ((k % 5) * 63 * CPAD + (k >= 5 ? 1 : 0))

    float rga[10], rgb[10];
    if (stg) {
        #pragma unroll
        for (int k = 0; k < 10; ++k) rga[k] = gp[GOFF(k)];
    }
    const float* gn = gp + (size_t)CCH * NH * NW;

    #pragma unroll 1
    for (int ch = 0; ch < NCHUNK; ++ch) {
        __syncthreads();   // previous chunk's readers done (also orders ssum zeroing)
        if (stg) {
            #pragma unroll
            for (int k = 0; k < 10; ++k) band[lbase + WOFF(k)] = rga[k];
        }
        __syncthreads();   // band ready
        if (ch + 1 < NCHUNK && stg) {       // issue next chunk's loads early (T14)
            #pragma unroll
            for (int k = 0; k < 10; ++k) rgb[k] = gn[GOFF(k)];
            gn += (size_t)CCH * NH * NW;
        }
        if (active) {
            #pragma unroll 1
            for (int c4 = 0; c4 < CCH / 4; ++c4) {
                float4 av[5];
                #pragma unroll
                for (int i = 0; i < 5; ++i)
                    av[i] = *(const float4*)&band[baseA + i * CPAD + c4 * 4];
                #pragma unroll
                for (int j = 0; j < 5; ++j) {
                    const float4 bv = *(const float4*)&band[baseB + j * CPAD + c4 * 4];
                    #pragma unroll
                    for (int i = 0; i < 5; ++i) {
                        acc[i * 5 + j] = fmaf(av[i].x, bv.x, acc[i * 5 + j]);
                        acc[i * 5 + j] = fmaf(av[i].y, bv.y, acc[i * 5 + j]);
                        acc[i * 5 + j] = fmaf(av[i].z, bv.z, acc[i * 5 + j]);
                        acc[i * 5 + j] = fmaf(av[i].w, bv.w, acc[i * 5 + j]);
                    }
                }
            }
        }
        #pragma unroll
        for (int k = 0; k < 10; ++k) rga[k] = rgb[k];
    }

    // ---- norms from diagonal blocks ----
    if (active && r1 == r2) {
        #pragma unroll
        for (int i = 0; i < 5; ++i)
            snorm[tile * 25 + r1 * 5 + i] = sqrtf(acc[i * 5 + i]);
    }
    __syncthreads();

    // ---- cosine partial row-sums, scattered via LDS atomics ----
    if (active) {
        float n1[5], n2[5];
        #pragma unroll
        for (int i = 0; i < 5; ++i) {
            n1[i] = snorm[tile * 25 + r1 * 5 + i];
            n2[i] = snorm[tile * 25 + r2 * 5 + i];
        }
        float rowp[5] = {0, 0, 0, 0, 0}, colp[5] = {0, 0, 0, 0, 0};
        #pragma unroll
        for (int i = 0; i < 5; ++i)
            #pragma unroll
            for (int j = 0; j < 5; ++j) {
                const float denom = fmaxf(n1[i] * n2[j], 1e-6f);
                const float cv = 1.0f - acc[i * 5 + j] / denom;
                rowp[i] += cv;
                if (r1 != r2) colp[j] += cv;
            }
        #pragma unroll
        for (int i = 0; i < 5; ++i) atomicAdd(&ssum[tile * 25 + r1 * 5 + i], rowp[i]);
        if (r1 != r2) {
            #pragma unroll
            for (int j = 0; j < 5; ++j) atomicAdd(&ssum[tile * 25 + r2 * 5 + j], colp[j]);
        }
    }
    __syncthreads();

    // ---- per-tile max of mean, then strip max -> per-b atomic ----
    if (t < OW) {
        float m = -1e30f;
        #pragma unroll
        for (int p = 0; p < 25; ++p) m = fmaxf(m, ssum[t * 25 + p]);
        snorm[t] = m * (1.0f / 25.0f);
    }
    __syncthreads();
    if (t == 0) {
        float m = snorm[0];
        for (int q = 1; q < OW; ++q) m = fmaxf(m, snorm[q]);
        atomicMax((int*)&tops[b], __float_as_int(m));  // values >= 0
    }
}

__global__ void finalize(const float* __restrict__ tops,
                         const int* __restrict__ label,
                         float* __restrict__ out) {
    if (threadIdx.x == 0) {
        float fs = 0.0f, rs = 0.0f, fc = 0.0f, rc = 0.0f;
        for (int b = 0; b < NB; ++b) {
            const float tb = tops[b];
            const float lb = (float)label[b];
            fs += tb * lb;          fc += lb;
            rs += tb * (1.0f - lb); rc += (1.0f - lb);
        }
        const float loss = 1.0f - fs / fc + rs / rc;
        out[0] = fmaxf(loss, 0.0f);
    }
}

extern "C" void kernel_launch(void* const* d_in, const int* in_sizes, int n_in,
                              void* d_out, int out_size, void* d_ws, size_t ws_size,
                              hipStream_t stream) {
    const float* feature = (const float*)d_in[0];
    const int* label     = (const int*)d_in[1];
    float* out  = (float*)d_out;
    float* tops = (float*)d_ws;   // 32 floats of scratch

    init_tops<<<1, 64, 0, stream>>>(tops);
    strip_kernel<<<NB * OH, 512, 0, stream>>>(feature, tops);
    finalize<<<1, 64, 0, stream>>>(tops, label, out);
}